// Round 1
// baseline (835.384 us; speedup 1.0000x reference)
//
#include <hip/hip_runtime.h>
#include <math.h>

// One-LDS-array design: stage input tile once, horizontal conv in registers,
// vertical conv via register scatter-accumulation. No intermediate LDS arrays,
// single barrier.
//
// Tile: 64 wide x 128 tall outputs per 256-thread block.
// Each thread: 4 cols (float4) x 8 rows. 16 x-chunks x 16 y-groups.
#define TX   64
#define RPT  8                 // output rows per thread
#define TYB  (16 * RPT)        // 128 output rows per block
#define IN_W 72                // TX + 8 (x-halo 4 each side keeps float4 alignment; conv needs 3)
#define IN_H (TYB + 6)         // 134 (y-halo 3 each side)

struct GaussCoefs {
    float g3[3];
    float g5[5];
    float g7[7];
};

__global__ __launch_bounds__(256, 4) void mgdf_kernel(
    const float* __restrict__ s,
    const float* __restrict__ w1p, const float* __restrict__ w2p,
    const float* __restrict__ w3p, const float* __restrict__ w4p,
    float* __restrict__ out,
    GaussCoefs gc, int Wd, int Hd)
{
    __shared__ float in_tile[IN_H][IN_W];

    const int tid   = threadIdx.x;
    const int plane = blockIdx.z;          // b*C + c
    const int x0    = blockIdx.x * TX;
    const int y0    = blockIdx.y * TYB;
    const float* sp = s + (size_t)plane * Hd * Wd;

    // Fold the diff chain: w1*s + w2*(s-s3) + w3*(s3-s5) + w4*(s5-s7)
    //   = (w1+w2)*s + (w3-w2)*s3 + (w4-w3)*s5 + (-w4)*s7
    const float w1 = *w1p, w2 = *w2p, w3 = *w3p, w4 = *w4p;
    const float a0 = w1 + w2;
    const float a3 = w3 - w2;
    const float a5 = w4 - w3;
    const float a7 = -w4;

    // Pre-scaled vertical weights (vertical pass then needs no final combine).
    float w7v[7], w5v[5], w3v[3];
    #pragma unroll
    for (int i = 0; i < 7; ++i) w7v[i] = a7 * gc.g7[i];
    #pragma unroll
    for (int i = 0; i < 5; ++i) w5v[i] = a5 * gc.g5[i];
    #pragma unroll
    for (int i = 0; i < 3; ++i) w3v[i] = a3 * gc.g3[i];

    // ---- Stage input tile (with halo, zero-padded at image borders) ----
    // 134 rows x 18 float4 chunks = 2412 tasks.
    for (int c = tid; c < IN_H * (IN_W / 4); c += 256) {
        const int r  = c / (IN_W / 4);
        const int c4 = c % (IN_W / 4);
        const int gy = y0 - 3 + r;
        const int gx = x0 - 4 + c4 * 4;
        float4 v = make_float4(0.f, 0.f, 0.f, 0.f);
        if (gy >= 0 && gy < Hd) {
            const float* rowp = sp + (size_t)gy * Wd;
            if (gx >= 0 && gx + 3 < Wd) {
                v = *(const float4*)(rowp + gx);
            } else {
                float tmp[4];
                #pragma unroll
                for (int j = 0; j < 4; ++j) {
                    const int x = gx + j;
                    tmp[j] = (x >= 0 && x < Wd) ? rowp[x] : 0.f;
                }
                v = make_float4(tmp[0], tmp[1], tmp[2], tmp[3]);
            }
        }
        *(float4*)&in_tile[r][c4 * 4] = v;
    }
    __syncthreads();

    // ---- Fused horizontal + vertical pass, all in registers ----
    const int tx  = tid & 15;      // x chunk (float4)
    const int tyg = tid >> 4;      // y group
    const int ty0 = tyg * RPT;     // first output row (tile-local) of this thread
    const int xb  = tx * 4;

    float acc[RPT][4];
    #pragma unroll
    for (int r = 0; r < RPT; ++r) {
        acc[r][0] = 0.f; acc[r][1] = 0.f; acc[r][2] = 0.f; acc[r][3] = 0.f;
    }

    // Input rows needed for outputs [ty0, ty0+RPT): in_tile rows ty0 .. ty0+RPT+5.
    #pragma unroll
    for (int ri = 0; ri < RPT + 6; ++ri) {
        const float* row = &in_tile[ty0 + ri][xb];
        const float4 va = *(const float4*)(row);
        const float4 vb = *(const float4*)(row + 4);
        const float4 vc = *(const float4*)(row + 8);
        const float v[12] = {va.x, va.y, va.z, va.w,
                             vb.x, vb.y, vb.z, vb.w,
                             vc.x, vc.y, vc.z, vc.w};

        // Horizontal convs for this input row (output x = x0 + xb + j, center v[j+4]).
        float h3v[4], h5v[4], h7v[4], sv[4];
        #pragma unroll
        for (int j = 0; j < 4; ++j) {
            float h7 = 0.f;
            #pragma unroll
            for (int i = 0; i < 7; ++i) h7 = fmaf(gc.g7[i], v[j + 1 + i], h7);
            float h5 = 0.f;
            #pragma unroll
            for (int i = 0; i < 5; ++i) h5 = fmaf(gc.g5[i], v[j + 2 + i], h5);
            float h3 = 0.f;
            #pragma unroll
            for (int i = 0; i < 3; ++i) h3 = fmaf(gc.g3[i], v[j + 3 + i], h3);
            h7v[j] = h7; h5v[j] = h5; h3v[j] = h3; sv[j] = v[j + 4];
        }

        // Scatter this input row into every output row it contributes to.
        // Output yo uses in_tile rows yo+iv (iv=0..6) with weight g7[iv]; so yo = ri - iv.
        #pragma unroll
        for (int iv = 0; iv < 7; ++iv) {
            const int yo = ri - iv;
            if (yo >= 0 && yo < RPT) {
                #pragma unroll
                for (int j = 0; j < 4; ++j) {
                    float t = fmaf(w7v[iv], h7v[j], acc[yo][j]);
                    if (iv >= 1 && iv <= 5) t = fmaf(w5v[iv - 1], h5v[j], t);
                    if (iv >= 2 && iv <= 4) t = fmaf(w3v[iv - 2], h3v[j], t);
                    if (iv == 3)            t = fmaf(a0, sv[j], t);
                    acc[yo][j] = t;
                }
            }
        }
    }

    // ---- Store ----
    float* outp = out + (size_t)plane * Hd * Wd;
    if (x0 + xb < Wd) {
        #pragma unroll
        for (int yo = 0; yo < RPT; ++yo) {
            const int gy = y0 + ty0 + yo;
            if (gy < Hd) {
                *(float4*)(outp + (size_t)gy * Wd + x0 + xb) =
                    make_float4(acc[yo][0], acc[yo][1], acc[yo][2], acc[yo][3]);
            }
        }
    }
}

static void fill_gauss(float* g, int k) {
    const double sigma = 0.3 * ((k - 1) * 0.5 - 1.0) + 0.8;
    double t[7], sum = 0.0;
    for (int i = 0; i < k; ++i) {
        const double x = (double)(i - k / 2);
        t[i] = exp(-x * x / (2.0 * sigma * sigma));
        sum += t[i];
    }
    for (int i = 0; i < k; ++i) g[i] = (float)(t[i] / sum);
}

extern "C" void kernel_launch(void* const* d_in, const int* in_sizes, int n_in,
                              void* d_out, int out_size, void* d_ws, size_t ws_size,
                              hipStream_t stream) {
    const float* s  = (const float*)d_in[0];
    const float* w1 = (const float*)d_in[1];
    const float* w2 = (const float*)d_in[2];
    const float* w3 = (const float*)d_in[3];
    const float* w4 = (const float*)d_in[4];
    float* out = (float*)d_out;

    const int Hd = 512, Wd = 512;
    const int planes = in_sizes[0] / (Hd * Wd);   // B*C = 192

    GaussCoefs gc;
    fill_gauss(gc.g3, 3);
    fill_gauss(gc.g5, 5);
    fill_gauss(gc.g7, 7);

    dim3 grid((Wd + TX - 1) / TX, (Hd + TYB - 1) / TYB, planes);
    mgdf_kernel<<<grid, 256, 0, stream>>>(s, w1, w2, w3, w4, out, gc, Wd, Hd);
}

// Round 2
// 421.068 us; speedup vs baseline: 1.9840x; 1.9840x over previous
//
#include <hip/hip_runtime.h>
#include <math.h>

// Fused separable multi-Gaussian, one LDS array, register scatter-accumulation.
// All accumulators / row values / coefficients are NAMED variables — zero
// runtime-indexed arrays, so nothing can fall to scratch (round-1 lesson).
//
// Tile: 64 wide x 64 tall outputs per 256-thread block.
// Thread: 4 cols (float4) x 4 rows. 16 x-chunks x 16 y-groups.
#define TX   64
#define RPT  4                 // output rows per thread
#define TYB  (16 * RPT)        // 64 output rows per block
#define IN_W 72                // TX + 8 (x-halo 4 each side, float4-aligned; conv needs 3)
#define IN_H (TYB + 6)         // 70 (y-halo 3 each side)

struct GaussCoefs {
    float g3[3];
    float g5[5];
    float g7[7];
};

// acc.{xyzw} += W * F.{xyzw}
#define ADD4(A, W, F) \
    A.x = fmaf((W), (F).x, A.x); A.y = fmaf((W), (F).y, A.y); \
    A.z = fmaf((W), (F).z, A.z); A.w = fmaf((W), (F).w, A.w);

#define DOT7(a,b,c,d,e,f,g) \
    fmaf(g7h0,(a), fmaf(g7h1,(b), fmaf(g7h2,(c), fmaf(g7h3,(d), \
    fmaf(g7h4,(e), fmaf(g7h5,(f), (g7h6)*(g)))))))
#define DOT5(a,b,c,d,e) \
    fmaf(g5h0,(a), fmaf(g5h1,(b), fmaf(g5h2,(c), fmaf(g5h3,(d), (g5h4)*(e)))))
#define DOT3(a,b,c) \
    fmaf(g3h0,(a), fmaf(g3h1,(b), (g3h2)*(c)))

// One input row: load 12 floats from LDS, compute h3/h5/h7/s for 4 output
// cols, then apply the (statically enumerated) vertical contributions.
#define STEP(RI, ...) { \
    const float* row_ = &in_tile[ty0 + (RI)][xb]; \
    const float4 va = *(const float4*)(row_); \
    const float4 vb = *(const float4*)(row_ + 4); \
    const float4 vc = *(const float4*)(row_ + 8); \
    const float v1 = va.y, v2 = va.z, v3 = va.w; \
    const float v4 = vb.x, v5 = vb.y, v6 = vb.z, v7 = vb.w; \
    const float v8 = vc.x, v9 = vc.y, v10 = vc.z; \
    float4 h7, h5, h3, sv; \
    h7.x = DOT7(v1,v2,v3,v4,v5,v6,v7); \
    h7.y = DOT7(v2,v3,v4,v5,v6,v7,v8); \
    h7.z = DOT7(v3,v4,v5,v6,v7,v8,v9); \
    h7.w = DOT7(v4,v5,v6,v7,v8,v9,v10); \
    h5.x = DOT5(v2,v3,v4,v5,v6); \
    h5.y = DOT5(v3,v4,v5,v6,v7); \
    h5.z = DOT5(v4,v5,v6,v7,v8); \
    h5.w = DOT5(v5,v6,v7,v8,v9); \
    h3.x = DOT3(v3,v4,v5); \
    h3.y = DOT3(v4,v5,v6); \
    h3.z = DOT3(v5,v6,v7); \
    h3.w = DOT3(v6,v7,v8); \
    sv = make_float4(v4, v5, v6, v7); \
    (void)h3; (void)h5; (void)sv; \
    __VA_ARGS__ \
}

__global__ __launch_bounds__(256) void mgdf_kernel(
    const float* __restrict__ s,
    const float* __restrict__ w1p, const float* __restrict__ w2p,
    const float* __restrict__ w3p, const float* __restrict__ w4p,
    float* __restrict__ out,
    GaussCoefs gc, int Wd, int Hd)
{
    __shared__ float in_tile[IN_H][IN_W];

    const int tid   = threadIdx.x;
    const int plane = blockIdx.z;          // b*C + c
    const int x0    = blockIdx.x * TX;
    const int y0    = blockIdx.y * TYB;
    const float* sp = s + (size_t)plane * Hd * Wd;

    // Fold diff chain: (w1+w2)*s + (w3-w2)*s3 + (w4-w3)*s5 + (-w4)*s7
    const float w1 = *w1p, w2 = *w2p, w3 = *w3p, w4 = *w4p;
    const float a0 = w1 + w2;
    const float a3 = w3 - w2;
    const float a5 = w4 - w3;
    const float a7 = -w4;

    // Horizontal (unscaled) coefficients — named scalars.
    const float g7h0 = gc.g7[0], g7h1 = gc.g7[1], g7h2 = gc.g7[2],
                g7h3 = gc.g7[3], g7h4 = gc.g7[4], g7h5 = gc.g7[5],
                g7h6 = gc.g7[6];
    const float g5h0 = gc.g5[0], g5h1 = gc.g5[1], g5h2 = gc.g5[2],
                g5h3 = gc.g5[3], g5h4 = gc.g5[4];
    const float g3h0 = gc.g3[0], g3h1 = gc.g3[1], g3h2 = gc.g3[2];

    // Vertical coefficients pre-scaled by the fold weights — named scalars.
    const float w7v0 = a7 * g7h0, w7v1 = a7 * g7h1, w7v2 = a7 * g7h2,
                w7v3 = a7 * g7h3, w7v4 = a7 * g7h4, w7v5 = a7 * g7h5,
                w7v6 = a7 * g7h6;
    const float w5v0 = a5 * g5h0, w5v1 = a5 * g5h1, w5v2 = a5 * g5h2,
                w5v3 = a5 * g5h3, w5v4 = a5 * g5h4;
    const float w3v0 = a3 * g3h0, w3v1 = a3 * g3h1, w3v2 = a3 * g3h2;

    // ---- Stage input tile (halo, zero-padded at image borders) ----
    // 70 rows x 18 float4 chunks = 1260 tasks.
    for (int c = tid; c < IN_H * (IN_W / 4); c += 256) {
        const int r  = c / (IN_W / 4);
        const int c4 = c % (IN_W / 4);
        const int gy = y0 - 3 + r;
        const int gx = x0 - 4 + c4 * 4;
        float4 v = make_float4(0.f, 0.f, 0.f, 0.f);
        if (gy >= 0 && gy < Hd) {
            const float* rowp = sp + (size_t)gy * Wd;
            if (gx >= 0 && gx + 3 < Wd) {
                v = *(const float4*)(rowp + gx);
            } else {
                float tmp[4];
                #pragma unroll
                for (int j = 0; j < 4; ++j) {
                    const int x = gx + j;
                    tmp[j] = (x >= 0 && x < Wd) ? rowp[x] : 0.f;
                }
                v = make_float4(tmp[0], tmp[1], tmp[2], tmp[3]);
            }
        }
        *(float4*)&in_tile[r][c4 * 4] = v;
    }
    __syncthreads();

    // ---- Fused horizontal + vertical pass, fully straight-line ----
    const int tx  = tid & 15;      // x chunk (float4)
    const int tyg = tid >> 4;      // y group
    const int ty0 = tyg * RPT;     // first output row (tile-local)
    const int xb  = tx * 4;

    float4 acc0 = make_float4(0.f, 0.f, 0.f, 0.f);
    float4 acc1 = make_float4(0.f, 0.f, 0.f, 0.f);
    float4 acc2 = make_float4(0.f, 0.f, 0.f, 0.f);
    float4 acc3 = make_float4(0.f, 0.f, 0.f, 0.f);

    // Output row yo consumes input rows yo+iv (iv=0..6); contributions:
    //   h7: w7v[iv] (iv 0..6) | h5: w5v[iv-1] (iv 1..5) | h3: w3v[iv-2] (iv 2..4) | s: a0 (iv==3)
    STEP(0, ADD4(acc0, w7v0, h7);)
    STEP(1, ADD4(acc0, w7v1, h7); ADD4(acc0, w5v0, h5);
            ADD4(acc1, w7v0, h7);)
    STEP(2, ADD4(acc0, w7v2, h7); ADD4(acc0, w5v1, h5); ADD4(acc0, w3v0, h3);
            ADD4(acc1, w7v1, h7); ADD4(acc1, w5v0, h5);
            ADD4(acc2, w7v0, h7);)
    STEP(3, ADD4(acc0, w7v3, h7); ADD4(acc0, w5v2, h5); ADD4(acc0, w3v1, h3); ADD4(acc0, a0, sv);
            ADD4(acc1, w7v2, h7); ADD4(acc1, w5v1, h5); ADD4(acc1, w3v0, h3);
            ADD4(acc2, w7v1, h7); ADD4(acc2, w5v0, h5);
            ADD4(acc3, w7v0, h7);)
    STEP(4, ADD4(acc0, w7v4, h7); ADD4(acc0, w5v3, h5); ADD4(acc0, w3v2, h3);
            ADD4(acc1, w7v3, h7); ADD4(acc1, w5v2, h5); ADD4(acc1, w3v1, h3); ADD4(acc1, a0, sv);
            ADD4(acc2, w7v2, h7); ADD4(acc2, w5v1, h5); ADD4(acc2, w3v0, h3);
            ADD4(acc3, w7v1, h7); ADD4(acc3, w5v0, h5);)
    STEP(5, ADD4(acc0, w7v5, h7); ADD4(acc0, w5v4, h5);
            ADD4(acc1, w7v4, h7); ADD4(acc1, w5v3, h5); ADD4(acc1, w3v2, h3);
            ADD4(acc2, w7v3, h7); ADD4(acc2, w5v2, h5); ADD4(acc2, w3v1, h3); ADD4(acc2, a0, sv);
            ADD4(acc3, w7v2, h7); ADD4(acc3, w5v1, h5); ADD4(acc3, w3v0, h3);)
    STEP(6, ADD4(acc0, w7v6, h7);
            ADD4(acc1, w7v5, h7); ADD4(acc1, w5v4, h5);
            ADD4(acc2, w7v4, h7); ADD4(acc2, w5v3, h5); ADD4(acc2, w3v2, h3);
            ADD4(acc3, w7v3, h7); ADD4(acc3, w5v2, h5); ADD4(acc3, w3v1, h3); ADD4(acc3, a0, sv);)
    STEP(7, ADD4(acc1, w7v6, h7);
            ADD4(acc2, w7v5, h7); ADD4(acc2, w5v4, h5);
            ADD4(acc3, w7v4, h7); ADD4(acc3, w5v3, h5); ADD4(acc3, w3v2, h3);)
    STEP(8, ADD4(acc2, w7v6, h7);
            ADD4(acc3, w7v5, h7); ADD4(acc3, w5v4, h5);)
    STEP(9, ADD4(acc3, w7v6, h7);)

    // ---- Store ----
    float* outp = out + (size_t)plane * Hd * Wd + (size_t)x0 + xb;
    const int gy0 = y0 + ty0;
    if (x0 + xb < Wd) {
        if (gy0 + 0 < Hd) *(float4*)(outp + (size_t)(gy0 + 0) * Wd) = acc0;
        if (gy0 + 1 < Hd) *(float4*)(outp + (size_t)(gy0 + 1) * Wd) = acc1;
        if (gy0 + 2 < Hd) *(float4*)(outp + (size_t)(gy0 + 2) * Wd) = acc2;
        if (gy0 + 3 < Hd) *(float4*)(outp + (size_t)(gy0 + 3) * Wd) = acc3;
    }
}

static void fill_gauss(float* g, int k) {
    const double sigma = 0.3 * ((k - 1) * 0.5 - 1.0) + 0.8;
    double t[7], sum = 0.0;
    for (int i = 0; i < k; ++i) {
        const double x = (double)(i - k / 2);
        t[i] = exp(-x * x / (2.0 * sigma * sigma));
        sum += t[i];
    }
    for (int i = 0; i < k; ++i) g[i] = (float)(t[i] / sum);
}

extern "C" void kernel_launch(void* const* d_in, const int* in_sizes, int n_in,
                              void* d_out, int out_size, void* d_ws, size_t ws_size,
                              hipStream_t stream) {
    const float* s  = (const float*)d_in[0];
    const float* w1 = (const float*)d_in[1];
    const float* w2 = (const float*)d_in[2];
    const float* w3 = (const float*)d_in[3];
    const float* w4 = (const float*)d_in[4];
    float* out = (float*)d_out;

    const int Hd = 512, Wd = 512;
    const int planes = in_sizes[0] / (Hd * Wd);   // B*C = 192

    GaussCoefs gc;
    fill_gauss(gc.g3, 3);
    fill_gauss(gc.g5, 5);
    fill_gauss(gc.g7, 7);

    dim3 grid((Wd + TX - 1) / TX, (Hd + TYB - 1) / TYB, planes);
    mgdf_kernel<<<grid, 256, 0, stream>>>(s, w1, w2, w3, w4, out, gc, Wd, Hd);
}